// Round 1
// baseline (368.747 us; speedup 1.0000x reference)
//
#include <hip/hip_runtime.h>

// TripletLoss: pairs are (2i, 2i+1); label[2i]==0 -> row 2i is positive.
// loss = mean_i relu(d(proto,pos_i) - d(proto,neg_i) + margin), fp32 scalar.
//
// R4 structure: same proven streaming core as R3 (wave-per-row coalesced
// float4 loads -> one 1KB row per instruction, 8 rows in flight with explicit
// 1-deep prefetch, signed per-lane delta, 4 interleaved butterflies), with
// three tail/launch-overhead fixes:
//   * 32 pairs per wave (64KB contiguous) -> 1024 blocks = exactly one
//     residency round at 4 blocks/CU (no round-boundary bubble)
//   * NO pre-zero kernel and NO same-address atomics: each block plain-stores
//     its partial to d_ws[blockIdx]; a trailing 1-block kernel reduces the
//     1024 partials (8KB, L2-hot, ~3us)
//   * labels prefetched one iteration ahead alongside the row prefetch

#define BLOCK_THREADS 256
#define WAVES_PER_BLOCK 4
#define PAIRS_PER_ITER 4
#define ITERS 8                    // 32 pairs per wave

__global__ __launch_bounds__(BLOCK_THREADS) void tl_main(
    const float* __restrict__ proto,
    const float* __restrict__ emb,
    const int* __restrict__ label,
    const int* __restrict__ margin_p,
    float* __restrict__ partial)
{
    __shared__ float swave[WAVES_PER_BLOCK];

    const int lane = threadIdx.x & 63;
    const int wv   = threadIdx.x >> 6;
    const int wave = blockIdx.x * WAVES_PER_BLOCK + wv;
    const int pair_base = wave * (PAIRS_PER_ITER * ITERS);

    // margin: robust to int32 or fp32 storage of the Python scalar 1
    int mbits = margin_p[0];
    float margin = (mbits >= -1000000 && mbits <= 1000000)
                       ? (float)mbits
                       : __int_as_float(mbits);

    // lane l holds proto[4l..4l+3]: one coalesced 1KB read, L2/L3-hot
    const float4 p = ((const float4*)proto)[lane];

    // this wave's 64 contiguous rows start here
    const float4* __restrict__ rows =
        (const float4*)(emb + (size_t)pair_base * 2 * 256);

    // labels for batch 0 (even-row label per pair)
    int lbc[PAIRS_PER_ITER];
    #pragma unroll
    for (int q = 0; q < PAIRS_PER_ITER; ++q)
        lbc[q] = label[2 * (pair_base + q)];

    // prime: batch 0 (8 rows; float4-index of row r = r*64 + lane)
    float4 x[2 * PAIRS_PER_ITER];
    #pragma unroll
    for (int r = 0; r < 8; ++r) x[r] = rows[r * 64 + lane];

    float acc = 0.0f;

    #pragma unroll
    for (int it = 0; it < ITERS; ++it) {
        // prefetch next batch (rows + labels) while we reduce the current one
        float4 y[8];
        int lbn[PAIRS_PER_ITER];
        if (it + 1 < ITERS) {
            const float4* nrows = rows + (it + 1) * 8 * 64;
            #pragma unroll
            for (int r = 0; r < 8; ++r) y[r] = nrows[r * 64 + lane];
            #pragma unroll
            for (int q = 0; q < PAIRS_PER_ITER; ++q)
                lbn[q] = label[2 * (pair_base + (it + 1) * PAIRS_PER_ITER + q)];
        }

        // per-lane signed delta for each of 4 pairs
        float s[PAIRS_PER_ITER];
        #pragma unroll
        for (int q = 0; q < PAIRS_PER_ITER; ++q) {
            const float4 e0 = x[2 * q];       // row 2*pair   (even: label lbc)
            const float4 e1 = x[2 * q + 1];   // row 2*pair+1
            float dx, d0, d1;
            dx = p.x - e0.x; d0 = dx * dx;
            dx = p.y - e0.y; d0 = fmaf(dx, dx, d0);
            dx = p.z - e0.z; d0 = fmaf(dx, dx, d0);
            dx = p.w - e0.w; d0 = fmaf(dx, dx, d0);
            dx = p.x - e1.x; d1 = dx * dx;
            dx = p.y - e1.y; d1 = fmaf(dx, dx, d1);
            dx = p.z - e1.z; d1 = fmaf(dx, dx, d1);
            dx = p.w - e1.w; d1 = fmaf(dx, dx, d1);
            s[q] = (lbc[q] == 0) ? (d0 - d1) : (d1 - d0);
        }

        // 4 independent 6-step butterflies, interleaved to hide latency
        #pragma unroll
        for (int off = 32; off > 0; off >>= 1) {
            #pragma unroll
            for (int q = 0; q < PAIRS_PER_ITER; ++q)
                s[q] += __shfl_xor(s[q], off, 64);
        }

        #pragma unroll
        for (int q = 0; q < PAIRS_PER_ITER; ++q) {
            const float loss = s[q] + margin;
            acc += (loss > 0.0f) ? loss : 0.0f;
        }

        if (it + 1 < ITERS) {
            #pragma unroll
            for (int r = 0; r < 8; ++r) x[r] = y[r];
            #pragma unroll
            for (int q = 0; q < PAIRS_PER_ITER; ++q) lbc[q] = lbn[q];
        }
    }

    // after a full butterfly every lane holds the wave total
    if (lane == 0) swave[wv] = acc;
    __syncthreads();

    if (threadIdx.x == 0) {
        // plain store of the block partial: no pre-zero, no atomics
        partial[blockIdx.x] =
            (swave[0] + swave[1]) + (swave[2] + swave[3]);
    }
}

__global__ __launch_bounds__(256) void tl_reduce(
    const float* __restrict__ partial,
    float* __restrict__ out,
    int nb,
    float inv_count)
{
    __shared__ float sw[4];
    const int lane = threadIdx.x & 63;
    const int wv   = threadIdx.x >> 6;

    float a = 0.0f;
    for (int i = threadIdx.x; i < nb; i += 256) a += partial[i];

    #pragma unroll
    for (int off = 32; off > 0; off >>= 1)
        a += __shfl_xor(a, off, 64);

    if (lane == 0) sw[wv] = a;
    __syncthreads();

    if (threadIdx.x == 0)
        out[0] = ((sw[0] + sw[1]) + (sw[2] + sw[3])) * inv_count;
}

extern "C" void kernel_launch(void* const* d_in, const int* in_sizes, int n_in,
                              void* d_out, int out_size, void* d_ws, size_t ws_size,
                              hipStream_t stream) {
    const float* proto = (const float*)d_in[0];
    const float* emb   = (const float*)d_in[1];
    const int*   label = (const int*)d_in[2];
    const int*   marg  = (const int*)d_in[3];
    float* out = (float*)d_out;

    const int n_rows  = in_sizes[2];      // 262144
    const int n_pairs = n_rows / 2;       // 131072

    // each wave: 32 pairs = 64 rows; each block: 4 waves = 256 rows
    const int blocks = n_rows / (WAVES_PER_BLOCK * PAIRS_PER_ITER * ITERS * 2); // 1024

    float* partial = (float*)d_ws;

    tl_main<<<blocks, BLOCK_THREADS, 0, stream>>>(proto, emb, label, marg, partial);
    tl_reduce<<<1, 256, 0, stream>>>(partial, out, blocks, 1.0f / (float)n_pairs);
}